// Round 16
// baseline (125.340 us; speedup 1.0000x reference)
//
#include <hip/hip_runtime.h>
#include <stdint.h>
#include <math.h>

#define B_SZ   2048
#define D_SZ   128
#define C_SZ   100000
#define S_SC   30.0f
#define C2LOG  43.2808512f                // 30*log2(e)
#define M2LOG  12.9837726f                // 9*log2(e)
#define A_QS   173.1234048f               // fp8 quant scale for f: C2LOG*4
#define B_QS   256.0f                     // fp8 quant scale for w
#define SCL_A  0x7D7D7D7Du                // e8m0 125 = 2^-2 (all 4 bytes)
#define SCL_B  0x77777777u                // e8m0 119 = 2^-8

// B-resident blocking: 782 blocks, each owns 128 W-columns for ALL 2048 rows.
// W normalized+quantized IN-KERNEL (no wn buffer, no rownorm kernel).
// B fragments live in 32 VGPRs for the whole kernel; A (fn) streams through
// a 2x8KB LDS ping-pong (R7-proven counted-vmcnt loop). Partials -> ps_lds
// (ds ops keep the vmcnt ledger clean), flushed coalesced as ps_t[cb][row].
#define CPB    128                        // cols per block
#define GRID_C ((C_SZ + CPB - 1)/CPB)     // 782
#define PAD_N  96.0f                      // (782*128-100000) pad cols -> 2^0 each
#define NSUB   32                         // 2048 rows / 64-row subtiles

typedef float f32x4 __attribute__((ext_vector_type(4)));
typedef int   i32x4 __attribute__((ext_vector_type(4)));
typedef int   i32x8 __attribute__((ext_vector_type(8)));
typedef unsigned char u8;

__device__ __forceinline__ void gload_lds16(const void* g, void* l) {
  __builtin_amdgcn_global_load_lds(
      (const __attribute__((address_space(1))) void*)g,
      (__attribute__((address_space(3))) void*)l, 16, 0, 0);
}

// ------- fused: normalize+quantize f rows AND exact fp32 label cos -------
__global__ void prep_f_kernel(const float* __restrict__ f,
                              const int* __restrict__ labels,
                              const float* __restrict__ w,
                              u8* __restrict__ fn, float* __restrict__ cosy) {
  int row  = (blockIdx.x * blockDim.x + threadIdx.x) >> 6;
  int lane = threadIdx.x & 63;
  if (row >= B_SZ) return;
  float2 fv = ((const float2*)(f + (size_t)row * D_SZ))[lane];
  float ff = fv.x * fv.x + fv.y * fv.y;
  #pragma unroll
  for (int m = 1; m < 64; m <<= 1) ff += __shfl_xor(ff, m, 64);
  float rn = A_QS / sqrtf(ff);
  int pk = __builtin_amdgcn_cvt_pk_fp8_f32(fv.x * rn, fv.y * rn, 0, false);
  ((unsigned short*)(fn + (size_t)row * D_SZ))[lane] = (unsigned short)(pk & 0xFFFF);

  int y = labels[row];
  float2 wv = ((const float2*)(w + (size_t)y * D_SZ))[lane];
  float d  = fv.x * wv.x + fv.y * wv.y;
  float ww = wv.x * wv.x + wv.y * wv.y;
  #pragma unroll
  for (int m = 1; m < 64; m <<= 1) {
    d  += __shfl_xor(d,  m, 64);
    ww += __shfl_xor(ww, m, 64);
  }
  if (lane == 0) {
    float c = d / (sqrtf(ff) * sqrtf(ww));
    c = fminf(1.0f, fmaxf(-1.0f, c));
    cosy[row] = c;
  }
}

// ---------------- fused: W-normalize + MX-FP8 GEMM + softmax partials ------
// 256 thr = 4 waves (2 row x 2 col). Wave tile per 64-row subtile: 32 rows
// (wr) x 64 cols (wc). bfrag[4] (cols wc*64+j*16+l15, K=128) held in regs.
// acc = 43.2808*cos; ps_lds[wc][row] += ... (each slot written exactly once).
__global__ __launch_bounds__(256, 4) void gemm_partial_kernel(
    const u8* __restrict__ fn, const float* __restrict__ w,
    float* __restrict__ ps_t) {
  __shared__ __align__(16) u8 lds[32768];
  float* ps_lds = (float*)(lds + 16384);       // [2][2048] floats, 16 KB

  const int tid  = threadIdx.x;
  const int lane = tid & 63;
  const int wid  = tid >> 6;
  const int wr   = wid >> 1, wc = wid & 1;
  const int cb   = blockIdx.x;                 // 0..781
  const int hi   = lane >> 4;
  const int l15  = lane & 15;

  // ---- prologue 1: normalize W chunk -> fp8 into lds[0..16K) ----
  // 16 lanes per W-row; c_loc = it*16 + wid*4 + hi covers 0..127.
  #pragma unroll
  for (int it = 0; it < 8; ++it) {
    int c_loc = it * 16 + wid * 4 + hi;
    int cg    = cb * CPB + c_loc;
    int crd   = cg < C_SZ ? cg : C_SZ - 1;
    const float4* wr4 = (const float4*)(w + (size_t)crd * D_SZ);
    float4 v0 = wr4[l15 * 2];
    float4 v1 = wr4[l15 * 2 + 1];
    float ssq = v0.x*v0.x + v0.y*v0.y + v0.z*v0.z + v0.w*v0.w
              + v1.x*v1.x + v1.y*v1.y + v1.z*v1.z + v1.w*v1.w;
    #pragma unroll
    for (int m = 1; m < 16; m <<= 1) ssq += __shfl_xor(ssq, m, 64);
    float rn = (cg < C_SZ) ? (B_QS * rsqrtf(ssq)) : 0.0f;   // pad cols -> 0
    int u0 = __builtin_amdgcn_cvt_pk_fp8_f32(v0.x*rn, v0.y*rn, 0, false);
    u0     = __builtin_amdgcn_cvt_pk_fp8_f32(v0.z*rn, v0.w*rn, u0, true);
    int u1 = __builtin_amdgcn_cvt_pk_fp8_f32(v1.x*rn, v1.y*rn, 0, false);
    u1     = __builtin_amdgcn_cvt_pk_fp8_f32(v1.z*rn, v1.w*rn, u1, true);
    int dst = c_loc * 128 + (((l15 >> 1) ^ (c_loc & 7)) * 16) + (l15 & 1) * 8;
    *(int2*)(lds + dst) = make_int2(u0, u1);
  }
  __builtin_amdgcn_s_barrier();

  // ---- prologue 2: bfrag -> registers (persistent all kernel) ----
  i32x8 bfrag[4];
  #pragma unroll
  for (int j = 0; j < 4; ++j) {
    int col = wc * 64 + j * 16 + l15;
    int s0  = (hi * 2)     ^ (col & 7);
    int s1  = (hi * 2 + 1) ^ (col & 7);
    i32x4 lo = *(const i32x4*)&lds[col * 128 + s0 * 16];
    i32x4 h4 = *(const i32x4*)&lds[col * 128 + s1 * 16];
    bfrag[j] = __builtin_shufflevector(lo, h4, 0, 1, 2, 3, 4, 5, 6, 7);
  }
  asm volatile("s_waitcnt lgkmcnt(0)" ::: "memory");
  __builtin_amdgcn_s_barrier();                // B-LDS dead; region reused for A

  // ---- A staging pointers: subtile = 64 rows x 128B = 8KB, 2 gloads/thr ----
  u8* Ab0 = lds;
  u8* Ab1 = lds + 8192;
  const u8* asrc[2];
  int adst[2];
  #pragma unroll
  for (int it = 0; it < 2; ++it) {
    int idx = it * 256 + tid;                  // 16B chunk id 0..511
    int r   = idx >> 3;                        // 0..63
    int s   = (idx & 7) ^ (r & 7);
    asrc[it] = fn + (size_t)r * D_SZ + s * 16;
    adst[it] = (it * 256 + (tid & ~63)) * 16;
  }
  // stage A(0) -> Ab1
  #pragma unroll
  for (int it = 0; it < 2; ++it)
    gload_lds16(asrc[it], Ab1 + adst[it]);

  const f32x4 zero4 = {0.f, 0.f, 0.f, 0.f};

  #pragma unroll 1
  for (int sub = 0; sub < NSUB; ++sub) {
    // prefetch A(sub+1) into the buffer freed by last iteration's end-barrier
    if (sub < NSUB - 1) {
      u8* dst = (sub & 1) ? Ab1 : Ab0;
      #pragma unroll
      for (int it = 0; it < 2; ++it) {
        asrc[it] += 64 * D_SZ;                 // advance one subtile
        gload_lds16(asrc[it], dst + adst[it]);
      }
      asm volatile("s_waitcnt vmcnt(2)" ::: "memory");  // A(sub) landed
    } else {
      asm volatile("s_waitcnt vmcnt(0)" ::: "memory");
    }
    __builtin_amdgcn_s_barrier();

    const u8* abuf = (sub & 1) ? Ab0 : Ab1;

    // afrag: rows wr*32 + i*16 + l15 of this subtile
    i32x8 af[2];
    #pragma unroll
    for (int i = 0; i < 2; ++i) {
      int row = wr * 32 + i * 16 + l15;
      int s0  = (hi * 2)     ^ (row & 7);
      int s1  = (hi * 2 + 1) ^ (row & 7);
      i32x4 lo = *(const i32x4*)&abuf[row * D_SZ + s0 * 16];
      i32x4 h4 = *(const i32x4*)&abuf[row * D_SZ + s1 * 16];
      af[i] = __builtin_shufflevector(lo, h4, 0, 1, 2, 3, 4, 5, 6, 7);
    }

    float sacc[2][4] = {};
    #pragma unroll
    for (int j = 0; j < 4; ++j) {
      #pragma unroll
      for (int i = 0; i < 2; ++i) {
        f32x4 acc;
        __builtin_amdgcn_s_setprio(1);
        acc = __builtin_amdgcn_mfma_scale_f32_16x16x128_f8f6f4(
            af[i], bfrag[j], zero4, 0, 0, 0, SCL_A, 0, SCL_B);
        __builtin_amdgcn_s_setprio(0);
        #pragma unroll
        for (int r = 0; r < 4; ++r)
          sacc[i][r] += __builtin_amdgcn_exp2f(acc[r]);
      }
    }

    // reduce over the 16 lanes sharing each row; write to ps_lds (unique slot)
    #pragma unroll
    for (int i = 0; i < 2; ++i)
      #pragma unroll
      for (int r = 0; r < 4; ++r) {
        float s = sacc[i][r];
        #pragma unroll
        for (int m = 1; m < 16; m <<= 1) s += __shfl_xor(s, m, 64);
        if (l15 == 0) {
          int rowl = sub * 64 + wr * 32 + i * 16 + hi * 4 + r;
          ps_lds[wc * 2048 + rowl] = s;
        }
      }

    asm volatile("s_waitcnt lgkmcnt(0)" ::: "memory");  // afrag reads + ds_writes done
    __builtin_amdgcn_s_barrier();   // all waves done with abuf before overwrite
  }

  // ---- flush: ps_t[cb][row] = wc0 + wc1, coalesced 8KB ----
  for (int k = tid; k < 2048; k += 256) {
    float v = ps_lds[k] + ps_lds[2048 + k];
    ps_t[(size_t)cb * 2048 + k] = v;
  }
}

// ---------------- merge1: partial column-sums over cb chunks ----------------
// grid 64 = 8 row-blocks x 8 cb-chunks; coalesced reads of ps_t[cb][row].
__global__ void merge1_kernel(const float* __restrict__ ps_t,
                              float* __restrict__ ps2) {
  int rb = blockIdx.x & 7, cc = blockIdx.x >> 3;
  int row = rb * 256 + threadIdx.x;
  int c0 = cc * 98;
  int c1 = c0 + 98 < GRID_C ? c0 + 98 : GRID_C;
  float s = 0.0f;
  for (int c = c0; c < c1; ++c) s += ps_t[(size_t)c * 2048 + row];
  ps2[cc * 2048 + row] = s;
}

// -------- merge2: final sums + per-row loss + deterministic mean ----------
__global__ void merge2_kernel(const float* __restrict__ ps2,
                              const float* __restrict__ cosy,
                              float* __restrict__ out) {
  __shared__ float red[256];
  int tid = threadIdx.x;
  float tot = 0.0f;
  for (int row = tid; row < B_SZ; row += 256) {
    float s = 0.0f;
    #pragma unroll
    for (int k = 0; k < 8; ++k) s += ps2[k * 2048 + row];
    float cy  = cosy[row];
    float zy2 = C2LOG * cy;
    s = s - PAD_N - exp2f(zy2) + exp2f(zy2 - M2LOG);  // pad + label margin swap
    s = fmaxf(s, 1e-30f);
    tot += logf(s) - 0.9f * (S_SC * cy - 9.0f);
  }
  red[tid] = tot;
  __syncthreads();
  for (int o = 128; o > 0; o >>= 1) {
    if (tid < o) red[tid] += red[tid + o];
    __syncthreads();
  }
  if (tid == 0) out[0] = red[0] / (float)B_SZ;
}

extern "C" void kernel_launch(void* const* d_in, const int* in_sizes, int n_in,
                              void* d_out, int out_size, void* d_ws, size_t ws_size,
                              hipStream_t stream) {
  const float* feat   = (const float*)d_in[0];
  const int*   labels = (const int*)d_in[1];
  const float* weight = (const float*)d_in[2];
  float* out = (float*)d_out;

  char* ws = (char*)d_ws;
  size_t off = 0;
  u8* fn = (u8*)(ws + off);          off += (size_t)B_SZ * D_SZ;        // 256 KB
  off = (off + 255) & ~(size_t)255;
  float* cosy = (float*)(ws + off);  off += (size_t)B_SZ * 4;
  off = (off + 255) & ~(size_t)255;
  float* ps_t = (float*)(ws + off);  off += (size_t)GRID_C * B_SZ * 4;  // 6.4 MB
  off = (off + 255) & ~(size_t)255;
  float* ps2 = (float*)(ws + off);   off += (size_t)8 * B_SZ * 4;       // 64 KB

  prep_f_kernel<<<(B_SZ + 3) / 4, 256, 0, stream>>>(feat, labels, weight, fn, cosy);
  gemm_partial_kernel<<<GRID_C, 256, 0, stream>>>(fn, weight, ps_t);
  merge1_kernel<<<64, 256, 0, stream>>>(ps_t, ps2);
  merge2_kernel<<<1, 256, 0, stream>>>(ps2, cosy, out);
}

// Round 17
// 68.056 us; speedup vs baseline: 1.8417x; 1.8417x over previous
//
#include <hip/hip_runtime.h>
#include <stdint.h>
#include <math.h>

#define B_SZ   2048
#define D_SZ   128
#define C_SZ   100000
#define S_SC   30.0f
#define C2LOG  43.2808512f                // 30*log2(e)
#define M2LOG  12.9837726f                // 9*log2(e)
#define A_QS   173.1234048f               // fp8 quant scale for f: C2LOG*4
#define B_QS   256.0f                     // fp8 quant scale for w
#define SCL_A  0x7D7D7D7Du                // e8m0 125 = 2^-2 (all 4 bytes)
#define SCL_B  0x77777777u                // e8m0 119 = 2^-8

// 8-wave blocks (512 thr = 4 row-waves x 2 col-waves), per-wave body = R7's
// proven shape (64 rows x 32 cols per subtile, afrag[4], 2 j-phases).
// Tests the "~2 workgroups/CU cap" hypothesis: bigger workgroups -> more
// resident waves. LDS 48KB: A 32KB linear + 2 x 8KB B ping-pong at +32K.
#define BM     256
#define BN     64
#define NSUB   16
#define CPB    (BN*NSUB)                  // 1024 cols per block
#define GRID_C ((C_SZ + CPB - 1)/CPB)     // 98
#define C_PAD  (GRID_C*CPB)               // 100352
#define POST_SUB 352.0f                   // pad cols contribute 2^0 = 1 each
#define NSLOT  (GRID_C*2)                 // 196 partial slots per row

typedef float f32x4 __attribute__((ext_vector_type(4)));
typedef int   i32x4 __attribute__((ext_vector_type(4)));
typedef int   i32x8 __attribute__((ext_vector_type(8)));
typedef unsigned char u8;

__device__ __forceinline__ void gload_lds16(const void* g, void* l) {
  __builtin_amdgcn_global_load_lds(
      (const __attribute__((address_space(1))) void*)g,
      (__attribute__((address_space(3))) void*)l, 16, 0, 0);
}

// ------- row L2-normalize (x qscale) -> fp8 e4m3; rows >= valid_rows zeroed -------
__global__ void rownorm_fp8_kernel(const float* __restrict__ in,
                                   u8* __restrict__ out, int rows,
                                   int valid_rows, float scale) {
  int row  = (blockIdx.x * blockDim.x + threadIdx.x) >> 6;
  int lane = threadIdx.x & 63;
  if (row >= rows) return;
  if (row >= valid_rows) {
    ((unsigned short*)(out + (size_t)row * D_SZ))[lane] = 0;
    return;
  }
  float2 v = ((const float2*)(in + (size_t)row * D_SZ))[lane];
  float ss = v.x * v.x + v.y * v.y;
  #pragma unroll
  for (int m = 1; m < 64; m <<= 1) ss += __shfl_xor(ss, m, 64);
  float rn = scale / sqrtf(ss);
  int pk = __builtin_amdgcn_cvt_pk_fp8_f32(v.x * rn, v.y * rn, 0, false);
  ((unsigned short*)(out + (size_t)row * D_SZ))[lane] = (unsigned short)(pk & 0xFFFF);
}

// ------- fused: normalize+quantize f rows AND exact fp32 label cos -------
__global__ void prep_f_kernel(const float* __restrict__ f,
                              const int* __restrict__ labels,
                              const float* __restrict__ w,
                              u8* __restrict__ fn, float* __restrict__ cosy) {
  int row  = (blockIdx.x * blockDim.x + threadIdx.x) >> 6;
  int lane = threadIdx.x & 63;
  if (row >= B_SZ) return;
  float2 fv = ((const float2*)(f + (size_t)row * D_SZ))[lane];
  float ff = fv.x * fv.x + fv.y * fv.y;
  #pragma unroll
  for (int m = 1; m < 64; m <<= 1) ff += __shfl_xor(ff, m, 64);
  float rn = A_QS / sqrtf(ff);
  int pk = __builtin_amdgcn_cvt_pk_fp8_f32(fv.x * rn, fv.y * rn, 0, false);
  ((unsigned short*)(fn + (size_t)row * D_SZ))[lane] = (unsigned short)(pk & 0xFFFF);

  int y = labels[row];
  float2 wv = ((const float2*)(w + (size_t)y * D_SZ))[lane];
  float d  = fv.x * wv.x + fv.y * wv.y;
  float ww = wv.x * wv.x + wv.y * wv.y;
  #pragma unroll
  for (int m = 1; m < 64; m <<= 1) {
    d  += __shfl_xor(d,  m, 64);
    ww += __shfl_xor(ww, m, 64);
  }
  if (lane == 0) {
    float c = d / (sqrtf(ff) * sqrtf(ww));
    c = fminf(1.0f, fmaxf(-1.0f, c));
    cosy[row] = c;
  }
}

// ---------------- fused MX-FP8 MFMA GEMM + softmax partials ----------------
// 512 thr = 8 waves (wr = wid>>1 in 0..3 row groups, wc = wid&1 col groups).
// Wave tile per subtile: 64 rows x 32 cols, K=128 in one mfma_scale.
// Per wave per subtile: 1 gload_lds (B staging share), 4 ds_read, 8 MFMA,
// 32 exp2. vmcnt ledger (per wave): prologue A:4 + B0:1 -> wait(1) pops A;
// loop: issue B(sub+1):1 -> outstanding 2 -> wait(1) pops B(sub).
// Two barriers per subtile (R7-proven): top (B landed) + bottom (buf consumed).
__global__ __launch_bounds__(512, 2) void gemm_partial_kernel(
    const u8* __restrict__ fn, const u8* __restrict__ wn,
    float* __restrict__ ps) {
  __shared__ __align__(16) u8 lds[49152];   // A: [0,32K) ; B bufs: +32K, +40K

  const int tid  = threadIdx.x;
  const int lane = tid & 63;
  const int wid  = tid >> 6;        // 0..7
  const int wr   = wid >> 1, wc = wid & 1;
  const int cb   = blockIdx.y;      // 0..97
  const int r0   = blockIdx.x * BM;
  const int hi   = lane >> 4;
  const int l15  = lane & 15;

  u8* Bbuf0 = lds + 32768;
  u8* Bbuf1 = lds + 40960;

  // ---- prologue: stage A (32KB) and B(0) concurrently ----
  #pragma unroll
  for (int it = 0; it < 4; ++it) {
    int idx = it * 512 + tid;                 // 16B chunk id (0..2047)
    int r   = idx >> 3;                       // 0..255
    int s   = (idx & 7) ^ (r & 7);            // pre-swizzled source slot
    gload_lds16(fn + (size_t)(r0 + r) * D_SZ + s * 16,
                lds + (it * 512 + (tid & ~63)) * 16);
  }
  const u8* bptr;                             // this thread's B staging src
  int bdst = (tid & ~63) * 16;                // wave-uniform dest within buffer
  {
    int cl = tid >> 3;                        // 0..63
    int s  = (tid & 7) ^ (cl & 7);
    bptr = wn + (size_t)(cb * CPB + cl) * D_SZ + s * 16;
    gload_lds16(bptr, Bbuf0 + bdst);          // B(0) -> buf0
    bptr += BN * D_SZ;                        // points at B(1) chunk
  }
  asm volatile("s_waitcnt vmcnt(1)" ::: "memory");   // A landed; B0 in flight
  __builtin_amdgcn_s_barrier();

  // ---- A fragments -> registers (rows r0+wr*64+i*16+l15, K span hi*32) ----
  i32x8 afrag[4];
  #pragma unroll
  for (int i = 0; i < 4; ++i) {
    int row = wr * 64 + i * 16 + l15;
    int s0  = (hi * 2)     ^ (row & 7);
    int s1  = (hi * 2 + 1) ^ (row & 7);
    i32x4 lo = *(const i32x4*)&lds[row * D_SZ + s0 * 16];
    i32x4 h4 = *(const i32x4*)&lds[row * D_SZ + s1 * 16];
    afrag[i] = __builtin_shufflevector(lo, h4, 0, 1, 2, 3, 4, 5, 6, 7);
  }
  asm volatile("s_waitcnt lgkmcnt(0)" ::: "memory");
  __builtin_amdgcn_sched_barrier(0);          // rule #18: pin afrag reads

  // hoisted bfrag slot offsets: col = wc*32 + j*16 + l15
  int boff[2][2];
  #pragma unroll
  for (int j = 0; j < 2; ++j) {
    int col = wc * 32 + j * 16 + l15;
    boff[j][0] = col * D_SZ + (((hi * 2)     ^ (col & 7)) * 16);
    boff[j][1] = col * D_SZ + (((hi * 2 + 1) ^ (col & 7)) * 16);
  }

  float sacc[4][4] = {};
  const f32x4 zero4 = {0.f, 0.f, 0.f, 0.f};

  #pragma unroll 1
  for (int sub = 0; sub < NSUB; ++sub) {
    // prefetch B(sub+1) into the other buffer (its old contents were consumed
    // in iteration sub-1, certified by that iteration's bottom barrier)
    if (sub < NSUB - 1) {
      u8* dst = ((sub + 1) & 1) ? Bbuf1 : Bbuf0;
      gload_lds16(bptr, dst + bdst);
      bptr += BN * D_SZ;
      asm volatile("s_waitcnt vmcnt(1)" ::: "memory");  // B(sub) landed
    } else {
      asm volatile("s_waitcnt vmcnt(0)" ::: "memory");
    }
    __builtin_amdgcn_s_barrier();             // all waves' B(sub) chunks in LDS

    const u8* bbuf = (sub & 1) ? Bbuf1 : Bbuf0;

    // read both j-phase fragments
    i32x8 b0, b1;
    {
      i32x4 lo0 = *(const i32x4*)&bbuf[boff[0][0]];
      i32x4 h40 = *(const i32x4*)&bbuf[boff[0][1]];
      i32x4 lo1 = *(const i32x4*)&bbuf[boff[1][0]];
      i32x4 h41 = *(const i32x4*)&bbuf[boff[1][1]];
      b0 = __builtin_shufflevector(lo0, h40, 0, 1, 2, 3, 4, 5, 6, 7);
      b1 = __builtin_shufflevector(lo1, h41, 0, 1, 2, 3, 4, 5, 6, 7);
    }
    asm volatile("s_waitcnt lgkmcnt(0)" ::: "memory");
    __builtin_amdgcn_sched_barrier(0);        // rule #18: MFMA must not hoist

    // ---- j0 ----
    {
      f32x4 acc[4];
      __builtin_amdgcn_s_setprio(1);
      #pragma unroll
      for (int i = 0; i < 4; ++i)
        acc[i] = __builtin_amdgcn_mfma_scale_f32_16x16x128_f8f6f4(
            afrag[i], b0, zero4, 0, 0, 0, SCL_A, 0, SCL_B);
      __builtin_amdgcn_s_setprio(0);
      #pragma unroll
      for (int i = 0; i < 4; ++i) {
        f32x4 a4 = acc[i];
        #pragma unroll
        for (int r = 0; r < 4; ++r)
          sacc[i][r] += __builtin_amdgcn_exp2f(a4[r]);
      }
    }
    // ---- j1 ----
    {
      f32x4 acc[4];
      __builtin_amdgcn_s_setprio(1);
      #pragma unroll
      for (int i = 0; i < 4; ++i)
        acc[i] = __builtin_amdgcn_mfma_scale_f32_16x16x128_f8f6f4(
            afrag[i], b1, zero4, 0, 0, 0, SCL_A, 0, SCL_B);
      __builtin_amdgcn_s_setprio(0);
      #pragma unroll
      for (int i = 0; i < 4; ++i) {
        f32x4 a4 = acc[i];
        #pragma unroll
        for (int r = 0; r < 4; ++r)
          sacc[i][r] += __builtin_amdgcn_exp2f(a4[r]);
      }
    }

    __builtin_amdgcn_s_barrier();             // bottom: buffer consumed
  }

  // ---- reduce across the 16 lanes sharing each row, write partials ----
  #pragma unroll
  for (int i = 0; i < 4; ++i)
    #pragma unroll
    for (int r = 0; r < 4; ++r) {
      float s = sacc[i][r];
      #pragma unroll
      for (int m = 1; m < 16; m <<= 1) s += __shfl_xor(s, m, 64);
      if (l15 == 0) {
        int rowg = r0 + wr * 64 + i * 16 + hi * 4 + r;
        ps[(size_t)rowg * NSLOT + cb * 2 + wc] = s;
      }
    }
}

// ---------------- merge partials -> per-row loss ----------------
__global__ void merge_kernel(const float* __restrict__ ps,
                             const float* __restrict__ cosy,
                             float* __restrict__ losses) {
  int row  = (blockIdx.x * blockDim.x + threadIdx.x) >> 6;
  int lane = threadIdx.x & 63;
  if (row >= B_SZ) return;
  float s = 0.0f;
  for (int k = lane; k < NSLOT; k += 64) s += ps[(size_t)row * NSLOT + k];
  #pragma unroll
  for (int m = 1; m < 64; m <<= 1) s += __shfl_xor(s, m, 64);
  if (lane == 0) {
    float cy  = cosy[row];
    float zy2 = C2LOG * cy;                 // log2-domain label logit
    s = s - POST_SUB - exp2f(zy2) + exp2f(zy2 - M2LOG);
    s = fmaxf(s, 1e-30f);
    float lse = logf(s);
    losses[row] = lse - 0.9f * (S_SC * cy - 9.0f);
  }
}

// ---------------- deterministic mean over B ----------------
__global__ void final_kernel(const float* __restrict__ losses, float* __restrict__ out) {
  __shared__ float red[256];
  int tid = threadIdx.x;
  float s = 0.0f;
  for (int k = tid; k < B_SZ; k += 256) s += losses[k];
  red[tid] = s;
  __syncthreads();
  for (int off = 128; off > 0; off >>= 1) {
    if (tid < off) red[tid] += red[tid + off];
    __syncthreads();
  }
  if (tid == 0) out[0] = red[0] / (float)B_SZ;
}

extern "C" void kernel_launch(void* const* d_in, const int* in_sizes, int n_in,
                              void* d_out, int out_size, void* d_ws, size_t ws_size,
                              hipStream_t stream) {
  const float* feat   = (const float*)d_in[0];
  const int*   labels = (const int*)d_in[1];
  const float* weight = (const float*)d_in[2];
  float* out = (float*)d_out;

  char* ws = (char*)d_ws;
  size_t off = 0;
  u8* wn = (u8*)(ws + off);          off += (size_t)C_PAD * D_SZ;      // 12.85 MB
  off = (off + 255) & ~(size_t)255;
  u8* fn = (u8*)(ws + off);          off += (size_t)B_SZ * D_SZ;       // 256 KB
  off = (off + 255) & ~(size_t)255;
  float* cosy = (float*)(ws + off);  off += (size_t)B_SZ * 4;
  off = (off + 255) & ~(size_t)255;
  float* ps = (float*)(ws + off);    off += (size_t)B_SZ * NSLOT * 4;  // 1.6 MB
  off = (off + 255) & ~(size_t)255;
  float* losses = (float*)(ws + off);

  rownorm_fp8_kernel<<<(C_PAD + 3) / 4, 256, 0, stream>>>(weight, wn, C_PAD, C_SZ, B_QS);
  prep_f_kernel<<<(B_SZ + 3) / 4, 256, 0, stream>>>(feat, labels, weight, fn, cosy);

  dim3 grid(B_SZ / BM, GRID_C);   // 8 x 98 = 784 blocks of 512 threads
  gemm_partial_kernel<<<grid, 512, 0, stream>>>(fn, wn, ps);

  merge_kernel<<<(B_SZ + 3) / 4, 256, 0, stream>>>(ps, cosy, losses);
  final_kernel<<<1, 256, 0, stream>>>(losses, out);
}

// Round 18
// 64.769 us; speedup vs baseline: 1.9352x; 1.0507x over previous
//
#include <hip/hip_runtime.h>
#include <stdint.h>
#include <math.h>

#define B_SZ   2048
#define D_SZ   128
#define C_SZ   100000
#define S_SC   30.0f
#define C2LOG  43.2808512f                // 30*log2(e)
#define M2LOG  12.9837726f                // 9*log2(e)
#define A_QS   173.1234048f               // fp8 quant scale for f: C2LOG*4
#define B_QS   256.0f                     // fp8 quant scale for w
#define SCL_A  0x7D7D7D7Du                // e8m0 125 = 2^-2 (all 4 bytes)
#define SCL_B  0x77777777u                // e8m0 119 = 2^-8

// R9-proven shape: BM=128 rows, 256 thr (4 waves 2x2);
// B subtile 64 cols x 128 fp8 = 8KB; LDS = 3 x 8KB rotation, 2-deep prefetch,
// counted vmcnt(2) (never 0 in main loop), one barrier per subtile.
// R17 delta vs R9: s_setprio pairs removed (m190: setprio hurts lockstep GEMM).
#define BM     128
#define BN     64
#define NSUB   16
#define CPB    (BN*NSUB)                  // 1024 cols per block
#define GRID_C ((C_SZ + CPB - 1)/CPB)     // 98
#define C_PAD  (GRID_C*CPB)               // 100352
// merge-time exact constant: 352 pad cols (2^0 each) + one zero-primed
// accumulator epilogue per wave (+16 per slot x 196 slots = 3136)
#define POST_SUB 3488.0f
#define NSLOT  (GRID_C*2)                 // 196 partial slots per row

typedef float f32x4 __attribute__((ext_vector_type(4)));
typedef int   i32x4 __attribute__((ext_vector_type(4)));
typedef int   i32x8 __attribute__((ext_vector_type(8)));
typedef unsigned char u8;

__device__ __forceinline__ void gload_lds16(const void* g, void* l) {
  __builtin_amdgcn_global_load_lds(
      (const __attribute__((address_space(1))) void*)g,
      (__attribute__((address_space(3))) void*)l, 16, 0, 0);
}

// ------- row L2-normalize (x qscale) -> fp8 e4m3; rows >= valid_rows zeroed -------
__global__ void rownorm_fp8_kernel(const float* __restrict__ in,
                                   u8* __restrict__ out, int rows,
                                   int valid_rows, float scale) {
  int row  = (blockIdx.x * blockDim.x + threadIdx.x) >> 6;
  int lane = threadIdx.x & 63;
  if (row >= rows) return;
  if (row >= valid_rows) {
    ((unsigned short*)(out + (size_t)row * D_SZ))[lane] = 0;
    return;
  }
  float2 v = ((const float2*)(in + (size_t)row * D_SZ))[lane];
  float ss = v.x * v.x + v.y * v.y;
  #pragma unroll
  for (int m = 1; m < 64; m <<= 1) ss += __shfl_xor(ss, m, 64);
  float rn = scale / sqrtf(ss);
  int pk = __builtin_amdgcn_cvt_pk_fp8_f32(v.x * rn, v.y * rn, 0, false);
  ((unsigned short*)(out + (size_t)row * D_SZ))[lane] = (unsigned short)(pk & 0xFFFF);
}

// ------- fused: normalize+quantize f rows AND exact fp32 label cos -------
__global__ void prep_f_kernel(const float* __restrict__ f,
                              const int* __restrict__ labels,
                              const float* __restrict__ w,
                              u8* __restrict__ fn, float* __restrict__ cosy) {
  int row  = (blockIdx.x * blockDim.x + threadIdx.x) >> 6;
  int lane = threadIdx.x & 63;
  if (row >= B_SZ) return;
  float2 fv = ((const float2*)(f + (size_t)row * D_SZ))[lane];
  float ff = fv.x * fv.x + fv.y * fv.y;
  #pragma unroll
  for (int m = 1; m < 64; m <<= 1) ff += __shfl_xor(ff, m, 64);
  float rn = A_QS / sqrtf(ff);
  int pk = __builtin_amdgcn_cvt_pk_fp8_f32(fv.x * rn, fv.y * rn, 0, false);
  ((unsigned short*)(fn + (size_t)row * D_SZ))[lane] = (unsigned short)(pk & 0xFFFF);

  int y = labels[row];
  float2 wv = ((const float2*)(w + (size_t)y * D_SZ))[lane];
  float d  = fv.x * wv.x + fv.y * wv.y;
  float ww = wv.x * wv.x + wv.y * wv.y;
  #pragma unroll
  for (int m = 1; m < 64; m <<= 1) {
    d  += __shfl_xor(d,  m, 64);
    ww += __shfl_xor(ww, m, 64);
  }
  if (lane == 0) {
    float c = d / (sqrtf(ff) * sqrtf(ww));
    c = fminf(1.0f, fmaxf(-1.0f, c));
    cosy[row] = c;
  }
}

// ---------------- fused MX-FP8 MFMA GEMM + softmax partials ----------------
// 256 thr = 4 waves (2 row x 2 col); wave tile 64 rows x 32 cols per subtile.
// K=128 in ONE mfma_scale per 16x16 tile. acc = 43.2808*cos; s += 2^acc.
// T3/T4: 3-buffer LDS rotation, prefetch 2 subtiles ahead, counted vmcnt(2)
// in the main loop (never 0). One barrier per subtile.
__global__ __launch_bounds__(256, 4) void gemm_partial_kernel(
    const u8* __restrict__ fn, const u8* __restrict__ wn,
    float* __restrict__ ps) {
  __shared__ __align__(16) u8 lds[3][BN * D_SZ];  // 3 x 8 KB

  const int tid  = threadIdx.x;
  const int lane = tid & 63;
  const int wid  = tid >> 6;
  const int wr   = wid >> 1, wc = wid & 1;
  const int cb   = blockIdx.y;
  const int r0   = blockIdx.x * BM;
  const int hi   = lane >> 4;
  const int l15  = lane & 15;

  // ---- B staging pointers (advance by BN*D_SZ per subtile) ----
  const u8* bsrc[2];
  int wch2[2];
  #pragma unroll
  for (int it = 0; it < 2; ++it) {
    int idx = it * 256 + tid;               // 16B chunk id (0..511)
    int cl  = idx >> 3;                     // 0..63
    int s   = (idx & 7) ^ (cl & 7);
    bsrc[it] = wn + (size_t)(cb * CPB + cl) * D_SZ + s * 16;
    wch2[it] = it * 256 + (tid & ~63);
  }

  // ---- prologue: stage A (16KB) into buf1+buf2; B(0) -> buf0 concurrently ----
  u8* aflat = &lds[1][0];
  #pragma unroll
  for (int it = 0; it < 4; ++it) {
    int idx  = it * 256 + tid;              // 16B chunk id (0..1023)
    int r    = idx >> 3;
    int s    = (idx & 7) ^ (r & 7);         // pre-swizzled source slot
    int wch  = it * 256 + (tid & ~63);      // wave-uniform LDS chunk base
    gload_lds16(fn + (size_t)(r0 + r) * D_SZ + s * 16, aflat + wch * 16);
  }
  #pragma unroll
  for (int it = 0; it < 2; ++it)
    gload_lds16(bsrc[it], &lds[0][wch2[it] * 16]);

  asm volatile("s_waitcnt vmcnt(2)" ::: "memory");   // A done; B(0) in flight
  __builtin_amdgcn_s_barrier();

  // ---- A fragments -> registers (rows r0+wr*64+i*16+l15, K span hi*32..+32) ----
  i32x8 afrag[4];
  #pragma unroll
  for (int i = 0; i < 4; ++i) {
    int row = wr * 64 + i * 16 + l15;
    int s0  = (hi * 2)     ^ (row & 7);
    int s1  = (hi * 2 + 1) ^ (row & 7);
    i32x4 lo = *(const i32x4*)&aflat[row * D_SZ + s0 * 16];
    i32x4 h4 = *(const i32x4*)&aflat[row * D_SZ + s1 * 16];
    afrag[i] = __builtin_shufflevector(lo, h4, 0, 1, 2, 3, 4, 5, 6, 7);
  }
  asm volatile("s_waitcnt lgkmcnt(0)" ::: "memory");  // afrag in regs
  __builtin_amdgcn_s_barrier();                       // buf1/buf2 free for B

  // stage B(1) -> buf1   (outstanding now: B0:2 + B1:2 = 4)
  #pragma unroll
  for (int it = 0; it < 2; ++it) {
    bsrc[it] += BN * D_SZ;
    gload_lds16(bsrc[it], &lds[1][wch2[it] * 16]);
  }

  // hoisted bfrag slot offsets: col = wc*32 + j*16 + l15
  int boff[2][2];
  #pragma unroll
  for (int j = 0; j < 2; ++j) {
    int col = wc * 32 + j * 16 + l15;
    boff[j][0] = col * D_SZ + (((hi * 2)     ^ (col & 7)) * 16);
    boff[j][1] = col * D_SZ + (((hi * 2 + 1) ^ (col & 7)) * 16);
  }

  float sacc[4][4] = {};
  f32x4 acc0[4];
  f32x4 acc1[4] = {};            // zero-primed; consumed once (exact, POST_SUB)
  const f32x4 zero4 = {0.f, 0.f, 0.f, 0.f};

  #pragma unroll 1
  for (int sub = 0; sub < NSUB; ++sub) {
    if (sub < NSUB - 1) {
      asm volatile("s_waitcnt vmcnt(2)" ::: "memory");  // B(sub) landed
    } else {
      asm volatile("s_waitcnt vmcnt(0)" ::: "memory");  // last: drain
    }
    __builtin_amdgcn_s_barrier();    // all waves done with buf[(sub-1)%3]

    // prefetch B(sub+2) into buf[(sub+2)%3] (the buffer freed by the barrier)
    if (sub < NSUB - 2) {
      u8* dst = &lds[(sub + 2) % 3][0];
      #pragma unroll
      for (int it = 0; it < 2; ++it) {
        bsrc[it] += BN * D_SZ;
        gload_lds16(bsrc[it], dst + wch2[it] * 16);
      }
    }

    const u8* bbuf = &lds[sub % 3][0];

    // ---- j0: MFMA cluster, then epilogue of previous acc1 ----
    i32x8 b0;
    {
      i32x4 lo = *(const i32x4*)&bbuf[boff[0][0]];
      i32x4 h4 = *(const i32x4*)&bbuf[boff[0][1]];
      b0 = __builtin_shufflevector(lo, h4, 0, 1, 2, 3, 4, 5, 6, 7);
    }
    #pragma unroll
    for (int i = 0; i < 4; ++i)
      acc0[i] = __builtin_amdgcn_mfma_scale_f32_16x16x128_f8f6f4(
          afrag[i], b0, zero4, 0, 0, 0, SCL_A, 0, SCL_B);
    #pragma unroll
    for (int i = 0; i < 4; ++i) {
      f32x4 a4 = acc1[i];
      #pragma unroll
      for (int r = 0; r < 4; ++r)
        sacc[i][r] += __builtin_amdgcn_exp2f(a4[r]);
    }

    // ---- j1: MFMA cluster, then epilogue of acc0 ----
    i32x8 b1;
    {
      i32x4 lo = *(const i32x4*)&bbuf[boff[1][0]];
      i32x4 h4 = *(const i32x4*)&bbuf[boff[1][1]];
      b1 = __builtin_shufflevector(lo, h4, 0, 1, 2, 3, 4, 5, 6, 7);
    }
    #pragma unroll
    for (int i = 0; i < 4; ++i)
      acc1[i] = __builtin_amdgcn_mfma_scale_f32_16x16x128_f8f6f4(
          afrag[i], b1, zero4, 0, 0, 0, SCL_A, 0, SCL_B);
    #pragma unroll
    for (int i = 0; i < 4; ++i) {
      f32x4 a4 = acc0[i];
      #pragma unroll
      for (int r = 0; r < 4; ++r)
        sacc[i][r] += __builtin_amdgcn_exp2f(a4[r]);
    }
  }

  // ---- tail: epilogue of the last subtile's acc1 ----
  #pragma unroll
  for (int i = 0; i < 4; ++i) {
    f32x4 a4 = acc1[i];
    #pragma unroll
    for (int r = 0; r < 4; ++r)
      sacc[i][r] += __builtin_amdgcn_exp2f(a4[r]);
  }

  // ---- reduce across the 16 lanes sharing each row, write partials ----
  #pragma unroll
  for (int i = 0; i < 4; ++i)
    #pragma unroll
    for (int r = 0; r < 4; ++r) {
      float s = sacc[i][r];
      #pragma unroll
      for (int m = 1; m < 16; m <<= 1) s += __shfl_xor(s, m, 64);
      if (l15 == 0) {
        int rowg = r0 + wr * 64 + i * 16 + hi * 4 + r;
        ps[(size_t)rowg * NSLOT + cb * 2 + wc] = s;
      }
    }
}

// ---------------- merge partials -> per-row loss ----------------
__global__ void merge_kernel(const float* __restrict__ ps,
                             const float* __restrict__ cosy,
                             float* __restrict__ losses) {
  int row  = (blockIdx.x * blockDim.x + threadIdx.x) >> 6;
  int lane = threadIdx.x & 63;
  if (row >= B_SZ) return;
  float s = 0.0f;
  for (int k = lane; k < NSLOT; k += 64) s += ps[(size_t)row * NSLOT + k];
  #pragma unroll
  for (int m = 1; m < 64; m <<= 1) s += __shfl_xor(s, m, 64);
  if (lane == 0) {
    float cy  = cosy[row];
    float zy2 = C2LOG * cy;                 // log2-domain label logit
    s = s - POST_SUB - exp2f(zy2) + exp2f(zy2 - M2LOG);
    s = fmaxf(s, 1e-30f);
    float lse = logf(s);
    losses[row] = lse - 0.9f * (S_SC * cy - 9.0f);
  }
}

// ---------------- deterministic mean over B ----------------
__global__ void final_kernel(const float* __restrict__ losses, float* __restrict__ out) {
  __shared__ float red[256];
  int tid = threadIdx.x;
  float s = 0.0f;
  for (int k = tid; k < B_SZ; k += 256) s += losses[k];
  red[tid] = s;
  __syncthreads();
  for (int off = 128; off > 0; off >>= 1) {
    if (tid < off) red[tid] += red[tid + off];
    __syncthreads();
  }
  if (tid == 0) out[0] = red[0] / (float)B_SZ;
}

extern "C" void kernel_launch(void* const* d_in, const int* in_sizes, int n_in,
                              void* d_out, int out_size, void* d_ws, size_t ws_size,
                              hipStream_t stream) {
  const float* feat   = (const float*)d_in[0];
  const int*   labels = (const int*)d_in[1];
  const float* weight = (const float*)d_in[2];
  float* out = (float*)d_out;

  char* ws = (char*)d_ws;
  size_t off = 0;
  u8* wn = (u8*)(ws + off);          off += (size_t)C_PAD * D_SZ;      // 12.85 MB
  off = (off + 255) & ~(size_t)255;
  u8* fn = (u8*)(ws + off);          off += (size_t)B_SZ * D_SZ;       // 256 KB
  off = (off + 255) & ~(size_t)255;
  float* cosy = (float*)(ws + off);  off += (size_t)B_SZ * 4;
  off = (off + 255) & ~(size_t)255;
  float* ps = (float*)(ws + off);    off += (size_t)B_SZ * NSLOT * 4;  // 1.6 MB
  off = (off + 255) & ~(size_t)255;
  float* losses = (float*)(ws + off);

  rownorm_fp8_kernel<<<(C_PAD + 3) / 4, 256, 0, stream>>>(weight, wn, C_PAD, C_SZ, B_QS);
  prep_f_kernel<<<(B_SZ + 3) / 4, 256, 0, stream>>>(feat, labels, weight, fn, cosy);

  dim3 grid(B_SZ / BM, GRID_C);   // x = row tiles (16), y = col tiles (98)
  gemm_partial_kernel<<<grid, 256, 0, stream>>>(fn, wn, ps);

  merge_kernel<<<(B_SZ + 3) / 4, 256, 0, stream>>>(ps, cosy, losses);
  final_kernel<<<1, 256, 0, stream>>>(losses, out);
}

// Round 19
// 62.471 us; speedup vs baseline: 2.0064x; 1.0368x over previous
//
#include <hip/hip_runtime.h>
#include <stdint.h>
#include <math.h>

#define B_SZ   2048
#define D_SZ   128
#define C_SZ   100000
#define S_SC   30.0f
#define C2LOG  43.2808512f                // 30*log2(e)
#define M2LOG  12.9837726f                // 9*log2(e)
#define A_QS   173.1234048f               // fp8 quant scale for f: C2LOG*4
#define B_QS   256.0f                     // fp8 quant scale for w
#define SCL_A  0x7D7D7D7Du                // e8m0 125 = 2^-2 (all 4 bytes)
#define SCL_B  0x77777777u                // e8m0 119 = 2^-8

// R9/R17-proven gemm shape: BM=128 rows, 256 thr (4 waves 2x2);
// B subtile 64 cols x 128 fp8 = 8KB; LDS = 3 x 8KB rotation, 2-deep prefetch,
// counted vmcnt(2), one barrier per subtile. R18 deltas: XCD-swizzled flat
// grid (wn L2 locality) + float4 rownorm. GEMM body byte-identical to R17.
#define BM     128
#define BN     64
#define NSUB   16
#define CPB    (BN*NSUB)                  // 1024 cols per block
#define GRID_C ((C_SZ + CPB - 1)/CPB)     // 98
#define C_PAD  (GRID_C*CPB)               // 100352
#define N_RT   (B_SZ/BM)                  // 16 row tiles
#define NBLK   (GRID_C*N_RT)              // 1568 = 8 XCD x 196
// merge-time exact constant: 352 pad cols (2^0 each) + one zero-primed
// accumulator epilogue per wave (+16 per slot x 196 slots = 3136)
#define POST_SUB 3488.0f
#define NSLOT  (GRID_C*2)                 // 196 partial slots per row

typedef float f32x4 __attribute__((ext_vector_type(4)));
typedef int   i32x4 __attribute__((ext_vector_type(4)));
typedef int   i32x8 __attribute__((ext_vector_type(8)));
typedef unsigned char u8;

__device__ __forceinline__ void gload_lds16(const void* g, void* l) {
  __builtin_amdgcn_global_load_lds(
      (const __attribute__((address_space(1))) void*)g,
      (__attribute__((address_space(3))) void*)l, 16, 0, 0);
}

// ------- row L2-normalize (x qscale) -> fp8 e4m3; 2 rows/wave, 16B/lane -------
__global__ void rownorm_fp8_kernel(const float* __restrict__ in,
                                   u8* __restrict__ out, int rows,
                                   int valid_rows, float scale) {
  int lane = threadIdx.x & 63;
  int half = lane >> 5;                    // 0..1: which row of this wave
  int l31  = lane & 31;
  int row  = ((blockIdx.x * blockDim.x + threadIdx.x) >> 6) * 2 + half;
  if (row >= rows) return;
  if (row >= valid_rows) {
    ((int2*)(out + (size_t)row * D_SZ))[l31] = make_int2(0, 0);
    return;
  }
  float4 v = ((const float4*)(in + (size_t)row * D_SZ))[l31];
  float ss = v.x * v.x + v.y * v.y + v.z * v.z + v.w * v.w;
  #pragma unroll
  for (int m = 1; m < 32; m <<= 1) ss += __shfl_xor(ss, m, 64);  // within half
  float rn = scale * rsqrtf(ss);
  int u0 = __builtin_amdgcn_cvt_pk_fp8_f32(v.x * rn, v.y * rn, 0, false);
  int u1 = __builtin_amdgcn_cvt_pk_fp8_f32(v.z * rn, v.w * rn, 0, false);
  ((int2*)(out + (size_t)row * D_SZ))[l31] =
      make_int2((u0 & 0xFFFF) | (u1 << 16), 0) ,
      make_int2(0,0);  // placeholder; real write below
}

// NOTE: the above packing was wrong-prone; use a clean dedicated kernel:
__global__ void rownorm_fp8v4_kernel(const float* __restrict__ in,
                                     u8* __restrict__ out, int rows,
                                     int valid_rows, float scale) {
  int lane = threadIdx.x & 63;
  int half = lane >> 5;
  int l31  = lane & 31;
  int row  = ((blockIdx.x * blockDim.x + threadIdx.x) >> 6) * 2 + half;
  if (row >= rows) return;
  unsigned* orow = (unsigned*)(out + (size_t)row * D_SZ);
  if (row >= valid_rows) {
    orow[l31] = 0u;
    return;
  }
  float4 v = ((const float4*)(in + (size_t)row * D_SZ))[l31];
  float ss = v.x * v.x + v.y * v.y + v.z * v.z + v.w * v.w;
  #pragma unroll
  for (int m = 1; m < 32; m <<= 1) ss += __shfl_xor(ss, m, 64);  // stays in half
  float rn = scale * rsqrtf(ss);
  int pk = __builtin_amdgcn_cvt_pk_fp8_f32(v.x * rn, v.y * rn, 0, false);
  pk     = __builtin_amdgcn_cvt_pk_fp8_f32(v.z * rn, v.w * rn, pk, true);
  orow[l31] = (unsigned)pk;                // 4 fp8 bytes per lane, coalesced
}

// ------- fused: normalize+quantize f rows AND exact fp32 label cos -------
__global__ void prep_f_kernel(const float* __restrict__ f,
                              const int* __restrict__ labels,
                              const float* __restrict__ w,
                              u8* __restrict__ fn, float* __restrict__ cosy) {
  int row  = (blockIdx.x * blockDim.x + threadIdx.x) >> 6;
  int lane = threadIdx.x & 63;
  if (row >= B_SZ) return;
  float2 fv = ((const float2*)(f + (size_t)row * D_SZ))[lane];
  float ff = fv.x * fv.x + fv.y * fv.y;
  #pragma unroll
  for (int m = 1; m < 64; m <<= 1) ff += __shfl_xor(ff, m, 64);
  float rn = A_QS / sqrtf(ff);
  int pk = __builtin_amdgcn_cvt_pk_fp8_f32(fv.x * rn, fv.y * rn, 0, false);
  ((unsigned short*)(fn + (size_t)row * D_SZ))[lane] = (unsigned short)(pk & 0xFFFF);

  int y = labels[row];
  float2 wv = ((const float2*)(w + (size_t)y * D_SZ))[lane];
  float d  = fv.x * wv.x + fv.y * wv.y;
  float ww = wv.x * wv.x + wv.y * wv.y;
  #pragma unroll
  for (int m = 1; m < 64; m <<= 1) {
    d  += __shfl_xor(d,  m, 64);
    ww += __shfl_xor(ww, m, 64);
  }
  if (lane == 0) {
    float c = d / (sqrtf(ff) * sqrtf(ww));
    c = fminf(1.0f, fmaxf(-1.0f, c));
    cosy[row] = c;
  }
}

// ---------------- fused MX-FP8 MFMA GEMM + softmax partials ----------------
// Flat grid 1568 with bijective XCD decode: xcd=bid&7, g=xcd*196+(bid>>3),
// cb=g>>4, rt=g&15 -> all 16 row-blocks of a cb land on ONE XCD (wn chunk
// fetched once per XCD L2 instead of 8x). GEMM body identical to R17.
__global__ __launch_bounds__(256, 4) void gemm_partial_kernel(
    const u8* __restrict__ fn, const u8* __restrict__ wn,
    float* __restrict__ ps) {
  __shared__ __align__(16) u8 lds[3][BN * D_SZ];  // 3 x 8 KB

  const int tid  = threadIdx.x;
  const int lane = tid & 63;
  const int wid  = tid >> 6;
  const int wr   = wid >> 1, wc = wid & 1;
  const int bid  = blockIdx.x;
  const int g    = (bid & 7) * (NBLK / 8) + (bid >> 3);
  const int cb   = g >> 4;                  // 0..97
  const int r0   = (g & 15) * BM;
  const int hi   = lane >> 4;
  const int l15  = lane & 15;

  // ---- B staging pointers (advance by BN*D_SZ per subtile) ----
  const u8* bsrc[2];
  int wch2[2];
  #pragma unroll
  for (int it = 0; it < 2; ++it) {
    int idx = it * 256 + tid;               // 16B chunk id (0..511)
    int cl  = idx >> 3;                     // 0..63
    int s   = (idx & 7) ^ (cl & 7);
    bsrc[it] = wn + (size_t)(cb * CPB + cl) * D_SZ + s * 16;
    wch2[it] = it * 256 + (tid & ~63);
  }

  // ---- prologue: stage A (16KB) into buf1+buf2; B(0) -> buf0 concurrently ----
  u8* aflat = &lds[1][0];
  #pragma unroll
  for (int it = 0; it < 4; ++it) {
    int idx  = it * 256 + tid;              // 16B chunk id (0..1023)
    int r    = idx >> 3;
    int s    = (idx & 7) ^ (r & 7);         // pre-swizzled source slot
    int wch  = it * 256 + (tid & ~63);      // wave-uniform LDS chunk base
    gload_lds16(fn + (size_t)(r0 + r) * D_SZ + s * 16, aflat + wch * 16);
  }
  #pragma unroll
  for (int it = 0; it < 2; ++it)
    gload_lds16(bsrc[it], &lds[0][wch2[it] * 16]);

  asm volatile("s_waitcnt vmcnt(2)" ::: "memory");   // A done; B(0) in flight
  __builtin_amdgcn_s_barrier();

  // ---- A fragments -> registers (rows r0+wr*64+i*16+l15, K span hi*32..+32) ----
  i32x8 afrag[4];
  #pragma unroll
  for (int i = 0; i < 4; ++i) {
    int row = wr * 64 + i * 16 + l15;
    int s0  = (hi * 2)     ^ (row & 7);
    int s1  = (hi * 2 + 1) ^ (row & 7);
    i32x4 lo = *(const i32x4*)&aflat[row * D_SZ + s0 * 16];
    i32x4 h4 = *(const i32x4*)&aflat[row * D_SZ + s1 * 16];
    afrag[i] = __builtin_shufflevector(lo, h4, 0, 1, 2, 3, 4, 5, 6, 7);
  }
  asm volatile("s_waitcnt lgkmcnt(0)" ::: "memory");  // afrag in regs
  __builtin_amdgcn_s_barrier();                       // buf1/buf2 free for B

  // stage B(1) -> buf1   (outstanding now: B0:2 + B1:2 = 4)
  #pragma unroll
  for (int it = 0; it < 2; ++it) {
    bsrc[it] += BN * D_SZ;
    gload_lds16(bsrc[it], &lds[1][wch2[it] * 16]);
  }

  // hoisted bfrag slot offsets: col = wc*32 + j*16 + l15
  int boff[2][2];
  #pragma unroll
  for (int j = 0; j < 2; ++j) {
    int col = wc * 32 + j * 16 + l15;
    boff[j][0] = col * D_SZ + (((hi * 2)     ^ (col & 7)) * 16);
    boff[j][1] = col * D_SZ + (((hi * 2 + 1) ^ (col & 7)) * 16);
  }

  float sacc[4][4] = {};
  f32x4 acc0[4];
  f32x4 acc1[4] = {};            // zero-primed; consumed once (exact, POST_SUB)
  const f32x4 zero4 = {0.f, 0.f, 0.f, 0.f};

  #pragma unroll 1
  for (int sub = 0; sub < NSUB; ++sub) {
    if (sub < NSUB - 1) {
      asm volatile("s_waitcnt vmcnt(2)" ::: "memory");  // B(sub) landed
    } else {
      asm volatile("s_waitcnt vmcnt(0)" ::: "memory");  // last: drain
    }
    __builtin_amdgcn_s_barrier();    // all waves done with buf[(sub-1)%3]

    // prefetch B(sub+2) into buf[(sub+2)%3] (the buffer freed by the barrier)
    if (sub < NSUB - 2) {
      u8* dst = &lds[(sub + 2) % 3][0];
      #pragma unroll
      for (int it = 0; it < 2; ++it) {
        bsrc[it] += BN * D_SZ;
        gload_lds16(bsrc[it], dst + wch2[it] * 16);
      }
    }

    const u8* bbuf = &lds[sub % 3][0];

    // ---- j0: MFMA cluster, then epilogue of previous acc1 ----
    i32x8 b0;
    {
      i32x4 lo = *(const i32x4*)&bbuf[boff[0][0]];
      i32x4 h4 = *(const i32x4*)&bbuf[boff[0][1]];
      b0 = __builtin_shufflevector(lo, h4, 0, 1, 2, 3, 4, 5, 6, 7);
    }
    #pragma unroll
    for (int i = 0; i < 4; ++i)
      acc0[i] = __builtin_amdgcn_mfma_scale_f32_16x16x128_f8f6f4(
          afrag[i], b0, zero4, 0, 0, 0, SCL_A, 0, SCL_B);
    #pragma unroll
    for (int i = 0; i < 4; ++i) {
      f32x4 a4 = acc1[i];
      #pragma unroll
      for (int r = 0; r < 4; ++r)
        sacc[i][r] += __builtin_amdgcn_exp2f(a4[r]);
    }

    // ---- j1: MFMA cluster, then epilogue of acc0 ----
    i32x8 b1;
    {
      i32x4 lo = *(const i32x4*)&bbuf[boff[1][0]];
      i32x4 h4 = *(const i32x4*)&bbuf[boff[1][1]];
      b1 = __builtin_shufflevector(lo, h4, 0, 1, 2, 3, 4, 5, 6, 7);
    }
    #pragma unroll
    for (int i = 0; i < 4; ++i)
      acc1[i] = __builtin_amdgcn_mfma_scale_f32_16x16x128_f8f6f4(
          afrag[i], b1, zero4, 0, 0, 0, SCL_A, 0, SCL_B);
    #pragma unroll
    for (int i = 0; i < 4; ++i) {
      f32x4 a4 = acc0[i];
      #pragma unroll
      for (int r = 0; r < 4; ++r)
        sacc[i][r] += __builtin_amdgcn_exp2f(a4[r]);
    }
  }

  // ---- tail: epilogue of the last subtile's acc1 ----
  #pragma unroll
  for (int i = 0; i < 4; ++i) {
    f32x4 a4 = acc1[i];
    #pragma unroll
    for (int r = 0; r < 4; ++r)
      sacc[i][r] += __builtin_amdgcn_exp2f(a4[r]);
  }

  // ---- reduce across the 16 lanes sharing each row, write partials ----
  #pragma unroll
  for (int i = 0; i < 4; ++i)
    #pragma unroll
    for (int r = 0; r < 4; ++r) {
      float s = sacc[i][r];
      #pragma unroll
      for (int m = 1; m < 16; m <<= 1) s += __shfl_xor(s, m, 64);
      if (l15 == 0) {
        int rowg = r0 + wr * 64 + i * 16 + hi * 4 + r;
        ps[(size_t)rowg * NSLOT + cb * 2 + wc] = s;
      }
    }
}

// ---------------- merge partials -> per-row loss ----------------
__global__ void merge_kernel(const float* __restrict__ ps,
                             const float* __restrict__ cosy,
                             float* __restrict__ losses) {
  int row  = (blockIdx.x * blockDim.x + threadIdx.x) >> 6;
  int lane = threadIdx.x & 63;
  if (row >= B_SZ) return;
  float s = 0.0f;
  for (int k = lane; k < NSLOT; k += 64) s += ps[(size_t)row * NSLOT + k];
  #pragma unroll
  for (int m = 1; m < 64; m <<= 1) s += __shfl_xor(s, m, 64);
  if (lane == 0) {
    float cy  = cosy[row];
    float zy2 = C2LOG * cy;                 // log2-domain label logit
    s = s - POST_SUB - exp2f(zy2) + exp2f(zy2 - M2LOG);
    s = fmaxf(s, 1e-30f);
    float lse = logf(s);
    losses[row] = lse - 0.9f * (S_SC * cy - 9.0f);
  }
}

// ---------------- deterministic mean over B ----------------
__global__ void final_kernel(const float* __restrict__ losses, float* __restrict__ out) {
  __shared__ float red[256];
  int tid = threadIdx.x;
  float s = 0.0f;
  for (int k = tid; k < B_SZ; k += 256) s += losses[k];
  red[tid] = s;
  __syncthreads();
  for (int off = 128; off > 0; off >>= 1) {
    if (tid < off) red[tid] += red[tid + off];
    __syncthreads();
  }
  if (tid == 0) out[0] = red[0] / (float)B_SZ;
}

extern "C" void kernel_launch(void* const* d_in, const int* in_sizes, int n_in,
                              void* d_out, int out_size, void* d_ws, size_t ws_size,
                              hipStream_t stream) {
  const float* feat   = (const float*)d_in[0];
  const int*   labels = (const int*)d_in[1];
  const float* weight = (const float*)d_in[2];
  float* out = (float*)d_out;

  char* ws = (char*)d_ws;
  size_t off = 0;
  u8* wn = (u8*)(ws + off);          off += (size_t)C_PAD * D_SZ;      // 12.85 MB
  off = (off + 255) & ~(size_t)255;
  u8* fn = (u8*)(ws + off);          off += (size_t)B_SZ * D_SZ;       // 256 KB
  off = (off + 255) & ~(size_t)255;
  float* cosy = (float*)(ws + off);  off += (size_t)B_SZ * 4;
  off = (off + 255) & ~(size_t)255;
  float* ps = (float*)(ws + off);    off += (size_t)B_SZ * NSLOT * 4;  // 1.6 MB
  off = (off + 255) & ~(size_t)255;
  float* losses = (float*)(ws + off);

  // 2 rows/wave, 8 rows per 256-thr block
  rownorm_fp8v4_kernel<<<(C_PAD + 7) / 8, 256, 0, stream>>>(weight, wn, C_PAD, C_SZ, B_QS);
  prep_f_kernel<<<(B_SZ + 3) / 4, 256, 0, stream>>>(feat, labels, weight, fn, cosy);

  gemm_partial_kernel<<<NBLK, 256, 0, stream>>>(fn, wn, ps);

  merge_kernel<<<(B_SZ + 3) / 4, 256, 0, stream>>>(ps, cosy, losses);
  final_kernel<<<1, 256, 0, stream>>>(losses, out);
}